// Round 1
// baseline (423.214 us; speedup 1.0000x reference)
//
#include <hip/hip_runtime.h>
#include <cstdint>
#include <cstddef>

typedef __attribute__((ext_vector_type(8))) short bf16x8;
typedef __attribute__((ext_vector_type(4))) float f32x4;
typedef __attribute__((ext_vector_type(4))) unsigned short u16x4;

__device__ __forceinline__ unsigned short f2bf(float f) {
  union { float f; unsigned int u; } v; v.f = f;
  unsigned int r = v.u + 0x7fffu + ((v.u >> 16) & 1u);
  return (unsigned short)(r >> 16);
}

// ---------------- convert / pack kernels ----------------
__global__ __launch_bounds__(256) void cvt_bf16_kernel(const float* __restrict__ src,
                                                       unsigned short* __restrict__ dst, int n) {
  int idx = (blockIdx.x * blockDim.x + threadIdx.x) * 4;
  if (idx >= n) return;
  const float* s = src + idx;
  u16x4 o = { f2bf(s[0]), f2bf(s[1]), f2bf(s[2]), f2bf(s[3]) };
  *(u16x4*)(dst + idx) = o;
}

// dst[r][0:F) = g[r][:], dst[r][F:2F) = u[r][:]  (one row per block)
__global__ __launch_bounds__(256) void pack_gu_kernel(const float* __restrict__ g,
                                                      const float* __restrict__ u,
                                                      unsigned short* __restrict__ dst, int F) {
  int r = blockIdx.x;
  const float* gr = g + (size_t)r * F;
  const float* ur = u + (size_t)r * F;
  unsigned short* d = dst + (size_t)r * 2 * F;
  for (int f = threadIdx.x * 4; f < F; f += blockDim.x * 4) {
    const float* gp = gr + f;
    u16x4 og = { f2bf(gp[0]), f2bf(gp[1]), f2bf(gp[2]), f2bf(gp[3]) };
    *(u16x4*)(d + f) = og;
    const float* up = ur + f;
    u16x4 ou = { f2bf(up[0]), f2bf(up[1]), f2bf(up[2]), f2bf(up[3]) };
    *(u16x4*)(d + F + f) = ou;
  }
}

// ---------------- router ----------------
__global__ __launch_bounds__(256) void router_kernel(const float* __restrict__ x,
                                                     const float* __restrict__ Wr,
                                                     const float* __restrict__ bias,
                                                     int* __restrict__ lists,
                                                     float* __restrict__ plist,
                                                     int* __restrict__ counts) {
  const int t = blockIdx.x;
  const int tid = threadIdx.x;
  const int wave = tid >> 6, lane = tid & 63;
  __shared__ float slog[8];
  const float* xr = x + (size_t)t * 1024;
  const int e0 = wave * 2, e1 = e0 + 1;
  float a0 = 0.f, a1 = 0.f;
  for (int d = lane; d < 1024; d += 64) {
    float xv = xr[d];
    a0 += xv * Wr[d * 8 + e0];
    a1 += xv * Wr[d * 8 + e1];
  }
  for (int off = 32; off > 0; off >>= 1) {
    a0 += __shfl_down(a0, off);
    a1 += __shfl_down(a1, off);
  }
  if (lane == 0) { slog[e0] = a0; slog[e1] = a1; }
  __syncthreads();
  if (tid == 0) {
    float v[8];
#pragma unroll
    for (int e = 0; e < 8; e++) v[e] = slog[e] + bias[e];
    int i0 = 0;
    for (int e = 1; e < 8; e++) if (v[e] > v[i0]) i0 = e;
    int i1 = (i0 == 0) ? 1 : 0;
    for (int e = 0; e < 8; e++) if (e != i0 && v[e] > v[i1]) i1 = e;
    float pa = 1.f / (1.f + __expf(v[i1] - v[i0]));
    float pb = 1.f - pa;
    int p0 = atomicAdd(&counts[i0], 1);
    lists[i0 * 2048 + p0] = t; plist[i0 * 2048 + p0] = pa;
    int p1 = atomicAdd(&counts[i1], 1);
    lists[i1 * 2048 + p1] = t; plist[i1 * 2048 + p1] = pb;
  }
}

__global__ void scan_kernel(const int* __restrict__ counts, int* __restrict__ offs) {
  if (threadIdx.x == 0) {
    int s = 0;
    for (int e = 0; e < 8; e++) { offs[e] = s; s += counts[e]; }
    offs[8] = s;
  }
}

// ---------------- silu(g) * u ----------------
__global__ __launch_bounds__(256) void silu_mul_kernel(const float* __restrict__ gu,
                                                       unsigned short* __restrict__ H,
                                                       int F, int R) {
  int r = blockIdx.x;
  if (r >= R) return;
  const float* g = gu + (size_t)r * 2 * F;
  const float* u = g + F;
  unsigned short* h = H + (size_t)r * F;
  for (int f = threadIdx.x; f < F; f += blockDim.x) {
    float gv = g[f], uv = u[f];
    float s = gv / (1.f + __expf(-gv));
    h[f] = f2bf(s * uv);
  }
}

// ---------------- tiled MFMA GEMM (NN, bf16 in, fp32 out) ----------------
// MODE 0: expert gate|up  : A = Xb gathered via lists[e], B = Wgu[e], C = gu + offs[e]*1024
// MODE 1: shared gate|up  : A = Xb, B = Sgu, C = gu (ldc 2048)
// MODE 2: expert down     : A = He + offs[e]*512, B = Wd[e], atomicAdd p*acc into out
// MODE 3: shared down     : A = Hs, B = Sd, C = out (plain store)
#define BM 128
#define BN 128
#define BKT 32
#define BKP 40

template <int MODE>
__global__ __launch_bounds__(256) void gemm_nn_kernel(
    const unsigned short* __restrict__ Aglob, const unsigned short* __restrict__ Bglob,
    float* __restrict__ Cout, float* __restrict__ outp,
    const int* __restrict__ lists, const float* __restrict__ plist,
    const int* __restrict__ counts, const int* __restrict__ offs) {
  const int e = blockIdx.z;
  int cnt, lda, K, N, ldc = 0;
  const unsigned short* A;
  const unsigned short* B;
  const int* list = nullptr;
  float* C = nullptr;
  const float* pr = nullptr;
  const int* tok = nullptr;

  if (MODE == 0) {
    cnt = counts[e]; A = Aglob; list = lists + e * 2048; lda = 1024; K = 1024; N = 1024;
    B = Bglob + (size_t)e * 1024 * 1024; C = Cout + (size_t)offs[e] * 1024; ldc = 1024;
  } else if (MODE == 1) {
    cnt = 2048; A = Aglob; lda = 1024; K = 1024; N = 2048; B = Bglob; C = Cout; ldc = 2048;
  } else if (MODE == 2) {
    cnt = counts[e]; A = Aglob + (size_t)offs[e] * 512; lda = 512; K = 512; N = 1024;
    B = Bglob + (size_t)e * 512 * 1024; tok = lists + e * 2048; pr = plist + e * 2048;
  } else {
    cnt = 2048; A = Aglob; lda = 1024; K = 1024; N = 1024; B = Bglob; C = Cout; ldc = 1024;
  }

  const int m0 = blockIdx.x * BM;
  if (m0 >= cnt) return;
  const int n0 = blockIdx.y * BN;

  __shared__ unsigned short As[BM * BKP];
  __shared__ unsigned short Bs[BN * BKP];

  const int tid = threadIdx.x;
  // A staging: 2 rows/thread, 8 bf16 each
  const int ar = tid >> 2;
  const int ac = (tid & 3) * 8;
  int arow0 = m0 + ar; if (arow0 >= cnt) arow0 = cnt - 1;
  int arow1 = m0 + ar + 64; if (arow1 >= cnt) arow1 = cnt - 1;
  size_t aoff0, aoff1;
  if (MODE == 0) { aoff0 = (size_t)list[arow0] * lda; aoff1 = (size_t)list[arow1] * lda; }
  else { aoff0 = (size_t)arow0 * lda; aoff1 = (size_t)arow1 * lda; }

  // B staging: thread reads 16 consecutive n at one k, writes transposed
  const int bk = tid & 31;
  const int bn = (tid >> 5) * 16;

  const int wave = tid >> 6;
  const int lane = tid & 63;
  const int wm = (wave & 1) * 64;
  const int wn = (wave >> 1) * 64;
  const int fl = lane & 15;
  const int q = lane >> 4;

  f32x4 acc[4][4];
  f32x4 zero = {0.f, 0.f, 0.f, 0.f};
#pragma unroll
  for (int i = 0; i < 4; i++)
#pragma unroll
    for (int j = 0; j < 4; j++) acc[i][j] = zero;

  for (int k0 = 0; k0 < K; k0 += BKT) {
    __syncthreads();
    bf16x8 va0 = *(const bf16x8*)(A + aoff0 + k0 + ac);
    bf16x8 va1 = *(const bf16x8*)(A + aoff1 + k0 + ac);
    *(bf16x8*)(&As[ar * BKP + ac]) = va0;
    *(bf16x8*)(&As[(ar + 64) * BKP + ac]) = va1;
    {
      const unsigned short* bp = B + (size_t)(k0 + bk) * N + n0 + bn;
      bf16x8 vb0 = *(const bf16x8*)(bp);
      bf16x8 vb1 = *(const bf16x8*)(bp + 8);
      unsigned short tmp[16];
      *(bf16x8*)(tmp) = vb0;
      *(bf16x8*)(tmp + 8) = vb1;
#pragma unroll
      for (int i = 0; i < 16; i++) Bs[(bn + i) * BKP + bk] = tmp[i];
    }
    __syncthreads();

    bf16x8 af[4], bfr[4];
#pragma unroll
    for (int i = 0; i < 4; i++) af[i] = *(const bf16x8*)(&As[(wm + i * 16 + fl) * BKP + q * 8]);
#pragma unroll
    for (int j = 0; j < 4; j++) bfr[j] = *(const bf16x8*)(&Bs[(wn + j * 16 + fl) * BKP + q * 8]);
#pragma unroll
    for (int i = 0; i < 4; i++)
#pragma unroll
      for (int j = 0; j < 4; j++)
        acc[i][j] = __builtin_amdgcn_mfma_f32_16x16x32_bf16(af[i], bfr[j], acc[i][j], 0, 0, 0);
  }

#pragma unroll
  for (int i = 0; i < 4; i++) {
#pragma unroll
    for (int j = 0; j < 4; j++) {
#pragma unroll
      for (int r = 0; r < 4; r++) {
        int row = wm + i * 16 + q * 4 + r;
        int grow = m0 + row;
        if (grow < cnt) {
          int col = n0 + wn + j * 16 + fl;
          float v = acc[i][j][r];
          if (MODE == 2) {
            atomicAdd(&outp[(size_t)tok[grow] * 1024 + col], pr[grow] * v);
          } else {
            C[(size_t)grow * ldc + col] = v;
          }
        }
      }
    }
  }
}

// ---------------- launch ----------------
extern "C" void kernel_launch(void* const* d_in, const int* in_sizes, int n_in,
                              void* d_out, int out_size, void* d_ws, size_t ws_size,
                              hipStream_t stream) {
  const float* x    = (const float*)d_in[0];
  const float* Wr   = (const float*)d_in[1];
  const float* Wg   = (const float*)d_in[2];
  const float* Wu   = (const float*)d_in[3];
  const float* Wd   = (const float*)d_in[4];
  const float* Sg   = (const float*)d_in[5];
  const float* Su   = (const float*)d_in[6];
  const float* Sd   = (const float*)d_in[7];
  const float* bias = (const float*)d_in[8];
  float* out = (float*)d_out;

  char* ws = (char*)d_ws;
  size_t o = 0;
  auto alloc = [&](size_t b) { char* p = ws + o; o += (b + 255) & ~(size_t)255; return p; };
  unsigned short* Xb  = (unsigned short*)alloc((size_t)2048 * 1024 * 2);
  unsigned short* Wgu = (unsigned short*)alloc((size_t)8 * 1024 * 1024 * 2);
  unsigned short* Wdb = (unsigned short*)alloc((size_t)8 * 512 * 1024 * 2);
  unsigned short* Sgu = (unsigned short*)alloc((size_t)1024 * 2048 * 2);
  unsigned short* Sdb = (unsigned short*)alloc((size_t)1024 * 1024 * 2);
  int*   lists  = (int*)alloc((size_t)8 * 2048 * 4);
  float* plist  = (float*)alloc((size_t)8 * 2048 * 4);
  int*   counts = (int*)alloc(64);
  int*   offs   = (int*)alloc(64);
  float* gu     = (float*)alloc((size_t)2048 * 2048 * 4);   // reused: shared then expert
  unsigned short* He = (unsigned short*)alloc((size_t)4096 * 512 * 2);
  unsigned short* Hs = (unsigned short*)alloc((size_t)2048 * 1024 * 2);

  hipMemsetAsync(counts, 0, 64, stream);

  cvt_bf16_kernel<<<2048, 256, 0, stream>>>(x, Xb, 2048 * 1024);
  pack_gu_kernel<<<8192, 256, 0, stream>>>(Wg, Wu, Wgu, 512);
  cvt_bf16_kernel<<<4096, 256, 0, stream>>>(Wd, Wdb, 8 * 512 * 1024);
  pack_gu_kernel<<<1024, 256, 0, stream>>>(Sg, Su, Sgu, 1024);
  cvt_bf16_kernel<<<1024, 256, 0, stream>>>(Sd, Sdb, 1024 * 1024);

  router_kernel<<<2048, 256, 0, stream>>>(x, Wr, bias, lists, plist, counts);
  scan_kernel<<<1, 64, 0, stream>>>(counts, offs);

  // shared-expert path first (plain store of out)
  gemm_nn_kernel<1><<<dim3(16, 16, 1), 256, 0, stream>>>(Xb, Sgu, gu, nullptr,
                                                         nullptr, nullptr, nullptr, nullptr);
  silu_mul_kernel<<<2048, 256, 0, stream>>>(gu, Hs, 1024, 2048);
  gemm_nn_kernel<3><<<dim3(16, 8, 1), 256, 0, stream>>>(Hs, Sdb, out, nullptr,
                                                        nullptr, nullptr, nullptr, nullptr);

  // routed experts (atomic-add into out)
  gemm_nn_kernel<0><<<dim3(16, 8, 8), 256, 0, stream>>>(Xb, Wgu, gu, nullptr,
                                                        lists, plist, counts, offs);
  silu_mul_kernel<<<4096, 256, 0, stream>>>(gu, He, 512, 4096);
  gemm_nn_kernel<2><<<dim3(16, 8, 8), 256, 0, stream>>>(He, Wdb, nullptr, out,
                                                        lists, plist, counts, offs);
}

// Round 2
// 326.291 us; speedup vs baseline: 1.2970x; 1.2970x over previous
//
#include <hip/hip_runtime.h>
#include <cstdint>
#include <cstddef>

typedef __attribute__((ext_vector_type(8))) short bf16x8;
typedef __attribute__((ext_vector_type(4))) float f32x4;
typedef __attribute__((ext_vector_type(4))) unsigned short u16x4;

#define AS1 __attribute__((address_space(1)))
#define AS3 __attribute__((address_space(3)))

__device__ __forceinline__ unsigned short f2bf(float f) {
  union { float f; unsigned int u; } v; v.f = f;
  unsigned int r = v.u + 0x7fffu + ((v.u >> 16) & 1u);
  return (unsigned short)(r >> 16);
}

__device__ __forceinline__ void gll16(const unsigned short* g, unsigned short* l) {
  __builtin_amdgcn_global_load_lds((const AS1 void*)g, (AS3 void*)l, 16, 0, 0);
}

// ---------------- x convert (no transpose) ----------------
__global__ __launch_bounds__(256) void cvt_bf16_kernel(const float* __restrict__ src,
                                                       unsigned short* __restrict__ dst, int n) {
  int idx = (blockIdx.x * blockDim.x + threadIdx.x) * 4;
  if (idx >= n) return;
  const float* s = src + idx;
  u16x4 o = { f2bf(s[0]), f2bf(s[1]), f2bf(s[2]), f2bf(s[3]) };
  *(u16x4*)(dst + idx) = o;
}

// ---------------- transpose + convert: dst[(c)*drp + r] = bf16(src[r*C + c]) ----------------
__global__ __launch_bounds__(256) void transpose_cvt_kernel(
    const float* __restrict__ src, unsigned short* __restrict__ dst,
    int R, int C, long sstride, long dstride, int drp) {
  src += (size_t)blockIdx.z * sstride;
  dst += (size_t)blockIdx.z * dstride;
  __shared__ float tile[32][33];
  const int c0 = blockIdx.x * 32, r0 = blockIdx.y * 32;
  const int tc = threadIdx.x & 31, tr = threadIdx.x >> 5;
#pragma unroll
  for (int i = 0; i < 4; i++) {
    int r = tr + i * 8;
    tile[r][tc] = src[(size_t)(r0 + r) * C + c0 + tc];
  }
  __syncthreads();
#pragma unroll
  for (int i = 0; i < 4; i++) {
    int cc = tr + i * 8;
    dst[(size_t)(c0 + cc) * drp + (r0 + tc)] = f2bf(tile[tc][cc]);
  }
}

// ---------------- router ----------------
__global__ __launch_bounds__(256) void router_kernel(const float* __restrict__ x,
                                                     const float* __restrict__ Wr,
                                                     const float* __restrict__ bias,
                                                     int* __restrict__ lists,
                                                     float* __restrict__ plist,
                                                     int* __restrict__ counts) {
  const int t = blockIdx.x;
  const int tid = threadIdx.x;
  const int wave = tid >> 6, lane = tid & 63;
  __shared__ float slog[8];
  const float* xr = x + (size_t)t * 1024;
  const int e0 = wave * 2, e1 = e0 + 1;
  float a0 = 0.f, a1 = 0.f;
  for (int d = lane; d < 1024; d += 64) {
    float xv = xr[d];
    a0 += xv * Wr[d * 8 + e0];
    a1 += xv * Wr[d * 8 + e1];
  }
  for (int off = 32; off > 0; off >>= 1) {
    a0 += __shfl_down(a0, off);
    a1 += __shfl_down(a1, off);
  }
  if (lane == 0) { slog[e0] = a0; slog[e1] = a1; }
  __syncthreads();
  if (tid == 0) {
    float v[8];
#pragma unroll
    for (int e = 0; e < 8; e++) v[e] = slog[e] + bias[e];
    int i0 = 0;
    for (int e = 1; e < 8; e++) if (v[e] > v[i0]) i0 = e;
    int i1 = (i0 == 0) ? 1 : 0;
    for (int e = 0; e < 8; e++) if (e != i0 && v[e] > v[i1]) i1 = e;
    float pa = 1.f / (1.f + __expf(v[i1] - v[i0]));
    float pb = 1.f - pa;
    int p0 = atomicAdd(&counts[i0], 1);
    lists[i0 * 2048 + p0] = t; plist[i0 * 2048 + p0] = pa;
    int p1 = atomicAdd(&counts[i1], 1);
    lists[i1 * 2048 + p1] = t; plist[i1 * 2048 + p1] = pb;
  }
}

__global__ void scan_kernel(const int* __restrict__ counts, int* __restrict__ offs) {
  if (threadIdx.x == 0) {
    int s = 0;
    for (int e = 0; e < 8; e++) { offs[e] = s; s += counts[e]; }
    offs[8] = s;
  }
}

// ---------------- fused TN GEMM, m97-style ----------------
// MODE 0: gate|up. z<8: A=Xb gathered, B=Wgu_t[e] (interleaved 2f/2f+1), H=He+offs[e]*512.
//                 z==8: A=Xb, B=Sgu_t [2048][1024], H=Hs.  Epilogue: silu(g)*u via shfl_xor.
// MODE 1: down.   z<8: A=He+offs[e]*512 (K=512), B=Wd_t[e] [1024][512], atomicAdd p*v.
//                 z==8: A=Hs (K=1024), B=Sd_t [1024][1024], atomicAdd v.
template <int MODE>
__global__ __launch_bounds__(256) void gemm_tn_kernel(
    const unsigned short* __restrict__ Xb, const unsigned short* __restrict__ He,
    const unsigned short* __restrict__ Hs, const unsigned short* __restrict__ Wgu,
    const unsigned short* __restrict__ Sgu, const unsigned short* __restrict__ Wd,
    const unsigned short* __restrict__ Sd, unsigned short* __restrict__ HeOut,
    unsigned short* __restrict__ HsOut, float* __restrict__ out,
    const int* __restrict__ lists, const float* __restrict__ plist,
    const int* __restrict__ counts, const int* __restrict__ offs) {
  const int ez = blockIdx.z;
  int cnt, lda, K;
  const unsigned short* A;
  const unsigned short* B;
  const int* list = nullptr;
  const int* tok = nullptr;
  const float* pr = nullptr;
  unsigned short* H = nullptr;
  int ldh = 0;

  if (MODE == 0) {
    if (ez < 8) {
      if (blockIdx.y >= 8) return;
      cnt = counts[ez]; A = Xb; list = lists + ez * 2048; lda = 1024; K = 1024;
      B = Wgu + (size_t)ez * 1024 * 1024; H = HeOut + (size_t)offs[ez] * 512; ldh = 512;
    } else {
      cnt = 2048; A = Xb; lda = 1024; K = 1024; B = Sgu; H = HsOut; ldh = 1024;
    }
  } else {
    if (ez < 8) {
      cnt = counts[ez]; A = He + (size_t)offs[ez] * 512; lda = 512; K = 512;
      B = Wd + (size_t)ez * 1024 * 512;
      tok = lists + ez * 2048; pr = plist + ez * 2048;
    } else {
      cnt = 2048; A = Hs; lda = 1024; K = 1024; B = Sd;
    }
  }

  const int m0 = blockIdx.x * 128;
  if (m0 >= cnt) return;
  const int n0 = blockIdx.y * 128;

  __shared__ unsigned short As[128 * 32];
  __shared__ unsigned short Bs[128 * 32];

  const int tid = threadIdx.x;
  const int srow = tid >> 2;            // 0..63
  const int scol = (tid & 3) * 8;       // 0/8/16/24
  const int wuni = (tid >> 6) * 512;    // wave-uniform LDS elem offset

  int r0 = m0 + srow; if (r0 >= cnt) r0 = cnt - 1;
  int r1 = m0 + srow + 64; if (r1 >= cnt) r1 = cnt - 1;
  size_t abase0, abase1;
  if (MODE == 0 && ez < 8) {
    abase0 = (size_t)list[r0] * lda; abase1 = (size_t)list[r1] * lda;
  } else {
    abase0 = (size_t)r0 * lda; abase1 = (size_t)r1 * lda;
  }
  const size_t bbase0 = (size_t)(n0 + srow) * K;
  const size_t bbase1 = (size_t)(n0 + srow + 64) * K;

  const int wave = tid >> 6;
  const int lane = tid & 63;
  const int wm = (wave & 1) * 64;
  const int wn = (wave >> 1) * 64;
  const int fl = lane & 15;
  const int q = lane >> 4;

  f32x4 acc[4][4];
  f32x4 zero = {0.f, 0.f, 0.f, 0.f};
#pragma unroll
  for (int i = 0; i < 4; i++)
#pragma unroll
    for (int j = 0; j < 4; j++) acc[i][j] = zero;

  for (int k0 = 0; k0 < K; k0 += 32) {
    __syncthreads();
    gll16(A + abase0 + k0 + scol, &As[wuni]);
    gll16(A + abase1 + k0 + scol, &As[2048 + wuni]);
    gll16(B + bbase0 + k0 + scol, &Bs[wuni]);
    gll16(B + bbase1 + k0 + scol, &Bs[2048 + wuni]);
    __syncthreads();

    bf16x8 af[4], bfr[4];
#pragma unroll
    for (int i = 0; i < 4; i++) af[i] = *(const bf16x8*)(&As[(wm + i * 16 + fl) * 32 + q * 8]);
#pragma unroll
    for (int j = 0; j < 4; j++) bfr[j] = *(const bf16x8*)(&Bs[(wn + j * 16 + fl) * 32 + q * 8]);
#pragma unroll
    for (int i = 0; i < 4; i++)
#pragma unroll
      for (int j = 0; j < 4; j++)
        acc[i][j] = __builtin_amdgcn_mfma_f32_16x16x32_bf16(af[i], bfr[j], acc[i][j], 0, 0, 0);
  }

  if (MODE == 0) {
    // silu(gate)*up across lane pairs; even col = gate(f=col/2), odd col = up
#pragma unroll
    for (int i = 0; i < 4; i++) {
#pragma unroll
      for (int j = 0; j < 4; j++) {
#pragma unroll
        for (int r = 0; r < 4; r++) {
          int grow = m0 + wm + i * 16 + q * 4 + r;
          float v = acc[i][j][r];
          float pv = __shfl_xor(v, 1);
          if ((lane & 1) == 0 && grow < cnt) {
            float s = v / (1.f + __expf(-v));
            int colh = (n0 + wn + j * 16 + fl) >> 1;
            H[(size_t)grow * ldh + colh] = f2bf(s * pv);
          }
        }
      }
    }
  } else {
#pragma unroll
    for (int i = 0; i < 4; i++) {
#pragma unroll
      for (int r = 0; r < 4; r++) {
        int grow = m0 + wm + i * 16 + q * 4 + r;
        if (grow >= cnt) continue;
        size_t obase; float p;
        if (ez < 8) { obase = (size_t)tok[grow] * 1024; p = pr[grow]; }
        else { obase = (size_t)grow * 1024; p = 1.f; }
#pragma unroll
        for (int j = 0; j < 4; j++) {
          int col = n0 + wn + j * 16 + fl;
          atomicAdd(&out[obase + col], p * acc[i][j][r]);
        }
      }
    }
  }
}

// ---------------- launch ----------------
extern "C" void kernel_launch(void* const* d_in, const int* in_sizes, int n_in,
                              void* d_out, int out_size, void* d_ws, size_t ws_size,
                              hipStream_t stream) {
  const float* x    = (const float*)d_in[0];
  const float* Wr   = (const float*)d_in[1];
  const float* Wg   = (const float*)d_in[2];
  const float* Wu   = (const float*)d_in[3];
  const float* Wd   = (const float*)d_in[4];
  const float* Sg   = (const float*)d_in[5];
  const float* Su   = (const float*)d_in[6];
  const float* Sd   = (const float*)d_in[7];
  const float* bias = (const float*)d_in[8];
  float* out = (float*)d_out;

  char* ws = (char*)d_ws;
  size_t o = 0;
  auto alloc = [&](size_t b) { char* p = ws + o; o += (b + 255) & ~(size_t)255; return p; };
  unsigned short* Xb   = (unsigned short*)alloc((size_t)2048 * 1024 * 2);
  unsigned short* WguT = (unsigned short*)alloc((size_t)8 * 1024 * 1024 * 2);  // [e][n(2f|2f+1)][k=1024]
  unsigned short* WdT  = (unsigned short*)alloc((size_t)8 * 1024 * 512 * 2);   // [e][n=1024][k=512]
  unsigned short* SguT = (unsigned short*)alloc((size_t)2048 * 1024 * 2);      // [n(2f|2f+1)][k=1024]
  unsigned short* SdT  = (unsigned short*)alloc((size_t)1024 * 1024 * 2);      // [n=1024][k=1024]
  int*   lists  = (int*)alloc((size_t)8 * 2048 * 4);
  float* plist  = (float*)alloc((size_t)8 * 2048 * 4);
  int*   counts = (int*)alloc(64);
  int*   offs   = (int*)alloc(64);
  unsigned short* He = (unsigned short*)alloc((size_t)4096 * 512 * 2);
  unsigned short* Hs = (unsigned short*)alloc((size_t)2048 * 1024 * 2);

  hipMemsetAsync(counts, 0, 64, stream);
  hipMemsetAsync(out, 0, (size_t)2048 * 1024 * 4, stream);

  cvt_bf16_kernel<<<2048, 256, 0, stream>>>(x, Xb, 2048 * 1024);
  // Wg [8][1024][512] -> WguT even rows (n=2f): drp=2048
  transpose_cvt_kernel<<<dim3(16, 32, 8), 256, 0, stream>>>(Wg, WguT, 1024, 512,
                                                            524288L, 1048576L, 2048);
  // Wu -> odd rows
  transpose_cvt_kernel<<<dim3(16, 32, 8), 256, 0, stream>>>(Wu, WguT + 1024, 1024, 512,
                                                            524288L, 1048576L, 2048);
  // Sg [1024][1024] -> SguT even rows
  transpose_cvt_kernel<<<dim3(32, 32, 1), 256, 0, stream>>>(Sg, SguT, 1024, 1024,
                                                            0L, 0L, 2048);
  transpose_cvt_kernel<<<dim3(32, 32, 1), 256, 0, stream>>>(Su, SguT + 1024, 1024, 1024,
                                                            0L, 0L, 2048);
  // Wd [8][512][1024] -> WdT [e][1024][512]
  transpose_cvt_kernel<<<dim3(32, 16, 8), 256, 0, stream>>>(Wd, WdT, 512, 1024,
                                                            524288L, 524288L, 512);
  // Sd [1024][1024] -> SdT
  transpose_cvt_kernel<<<dim3(32, 32, 1), 256, 0, stream>>>(Sd, SdT, 1024, 1024,
                                                            0L, 0L, 1024);

  router_kernel<<<2048, 256, 0, stream>>>(x, Wr, bias, lists, plist, counts);
  scan_kernel<<<1, 64, 0, stream>>>(counts, offs);

  gemm_tn_kernel<0><<<dim3(16, 16, 9), 256, 0, stream>>>(
      Xb, He, Hs, WguT, SguT, WdT, SdT, He, Hs, out, lists, plist, counts, offs);
  gemm_tn_kernel<1><<<dim3(16, 8, 9), 256, 0, stream>>>(
      Xb, He, Hs, WguT, SguT, WdT, SdT, He, Hs, out, lists, plist, counts, offs);
}

// Round 3
// 249.965 us; speedup vs baseline: 1.6931x; 1.3053x over previous
//
#include <hip/hip_runtime.h>
#include <cstdint>
#include <cstddef>

typedef __attribute__((ext_vector_type(8))) short bf16x8;
typedef __attribute__((ext_vector_type(4))) float f32x4;
typedef __attribute__((ext_vector_type(4))) unsigned short u16x4;

#define AS1 __attribute__((address_space(1)))
#define AS3 __attribute__((address_space(3)))

__device__ __forceinline__ unsigned short f2bf(float f) {
  union { float f; unsigned int u; } v; v.f = f;
  unsigned int r = v.u + 0x7fffu + ((v.u >> 16) & 1u);
  return (unsigned short)(r >> 16);
}

__device__ __forceinline__ void gll16(const unsigned short* g, unsigned short* l) {
  __builtin_amdgcn_global_load_lds((const AS1 void*)g, (AS3 void*)l, 16, 0, 0);
}

// ---------------- x convert ----------------
__global__ __launch_bounds__(256) void cvt_bf16_kernel(const float* __restrict__ src,
                                                       unsigned short* __restrict__ dst, int n) {
  int idx = (blockIdx.x * blockDim.x + threadIdx.x) * 4;
  if (idx >= n) return;
  const float* s = src + idx;
  u16x4 o = { f2bf(s[0]), f2bf(s[1]), f2bf(s[2]), f2bf(s[3]) };
  *(u16x4*)(dst + idx) = o;
}

// ---------------- transpose + convert ----------------
__global__ __launch_bounds__(256) void transpose_cvt_kernel(
    const float* __restrict__ src, unsigned short* __restrict__ dst,
    int R, int C, long sstride, long dstride, int drp) {
  src += (size_t)blockIdx.z * sstride;
  dst += (size_t)blockIdx.z * dstride;
  __shared__ float tile[32][33];
  const int c0 = blockIdx.x * 32, r0 = blockIdx.y * 32;
  const int tc = threadIdx.x & 31, tr = threadIdx.x >> 5;
#pragma unroll
  for (int i = 0; i < 4; i++) {
    int r = tr + i * 8;
    tile[r][tc] = src[(size_t)(r0 + r) * C + c0 + tc];
  }
  __syncthreads();
#pragma unroll
  for (int i = 0; i < 4; i++) {
    int cc = tr + i * 8;
    dst[(size_t)(c0 + cc) * drp + (r0 + tc)] = f2bf(tile[tc][cc]);
  }
}

// ---------------- router: logits (one wave per token) ----------------
__global__ __launch_bounds__(256) void logits_kernel(const float* __restrict__ x,
                                                     const float* __restrict__ Wr,
                                                     float* __restrict__ logits) {
  const int t = blockIdx.x * 4 + (threadIdx.x >> 6);
  const int lane = threadIdx.x & 63;
  const float* xr = x + (size_t)t * 1024;
  float acc[8];
#pragma unroll
  for (int e = 0; e < 8; e++) acc[e] = 0.f;
#pragma unroll
  for (int i = 0; i < 16; i++) {
    int d = lane + i * 64;
    float xv = xr[d];
    const float4* w = (const float4*)(Wr + d * 8);
    float4 w0 = w[0], w1 = w[1];
    acc[0] += xv * w0.x; acc[1] += xv * w0.y; acc[2] += xv * w0.z; acc[3] += xv * w0.w;
    acc[4] += xv * w1.x; acc[5] += xv * w1.y; acc[6] += xv * w1.z; acc[7] += xv * w1.w;
  }
#pragma unroll
  for (int off = 32; off > 0; off >>= 1)
#pragma unroll
    for (int e = 0; e < 8; e++) acc[e] += __shfl_down(acc[e], off);
  if (lane == 0) {
#pragma unroll
    for (int e = 0; e < 8; e++) logits[t * 8 + e] = acc[e];
  }
}

// ---------------- router: assignment (single block, LDS atomics) ----------------
__global__ __launch_bounds__(1024) void assign_kernel(
    const float* __restrict__ logits, const float* __restrict__ bias,
    int* __restrict__ list, int* __restrict__ ridx, float* __restrict__ rp,
    int* __restrict__ counts_g, int* __restrict__ offs_g) {
  __shared__ int cnt[8];
  __shared__ int offs[9];
  const int tid = threadIdx.x;
  if (tid < 8) cnt[tid] = 0;
  __syncthreads();
  int te[2][2], tpos[2][2];
  float tp[2][2];
#pragma unroll
  for (int it = 0; it < 2; it++) {
    int t = tid + it * 1024;
    float v[8];
#pragma unroll
    for (int e = 0; e < 8; e++) v[e] = logits[t * 8 + e] + bias[e];
    int i0 = 0;
#pragma unroll
    for (int e = 1; e < 8; e++) if (v[e] > v[i0]) i0 = e;
    int i1 = (i0 == 0) ? 1 : 0;
#pragma unroll
    for (int e = 0; e < 8; e++) if (e != i0 && v[e] > v[i1]) i1 = e;
    float pa = 1.f / (1.f + __expf(v[i1] - v[i0]));
    te[it][0] = i0; te[it][1] = i1;
    tp[it][0] = pa; tp[it][1] = 1.f - pa;
    tpos[it][0] = atomicAdd(&cnt[i0], 1);
    tpos[it][1] = atomicAdd(&cnt[i1], 1);
  }
  __syncthreads();
  if (tid == 0) {
    int s = 0;
#pragma unroll
    for (int e = 0; e < 8; e++) { offs[e] = s; s += cnt[e]; }
    offs[8] = s;
#pragma unroll
    for (int e = 0; e < 8; e++) { counts_g[e] = cnt[e]; offs_g[e] = offs[e]; }
    offs_g[8] = s;
  }
  __syncthreads();
#pragma unroll
  for (int it = 0; it < 2; it++) {
    int t = tid + it * 1024;
#pragma unroll
    for (int k = 0; k < 2; k++) {
      int grow = offs[te[it][k]] + tpos[it][k];
      list[grow] = t;
      ridx[t * 2 + k] = grow;
      rp[t * 2 + k] = tp[it][k];
    }
  }
}

// ---------------- fused TN GEMM ----------------
// MODE 0: gate|up. z<8: A=Xb gathered via list, B=WguT[e], H=He+offs[e]*512 (bf16).
//                 z==8: A=Xb, B=SguT, H=Hs.  Epilogue: silu(g)*u via shfl_xor.
// MODE 1: down.   z<8: A=He+offs[e]*512 (K=512), B=WdT[e], D=De+offs[e]*1024 (fp32 plain).
//                 z==8: A=Hs (K=1024), B=SdT, D=Ds.
template <int MODE>
__global__ __launch_bounds__(256) void gemm_tn_kernel(
    const unsigned short* __restrict__ Xb, const unsigned short* __restrict__ He,
    const unsigned short* __restrict__ Hs, const unsigned short* __restrict__ Wgu,
    const unsigned short* __restrict__ Sgu, const unsigned short* __restrict__ Wd,
    const unsigned short* __restrict__ Sd, unsigned short* __restrict__ HeOut,
    unsigned short* __restrict__ HsOut, float* __restrict__ De, float* __restrict__ Ds,
    const int* __restrict__ list, const int* __restrict__ counts,
    const int* __restrict__ offs) {
  const int ez = blockIdx.z;
  int cnt, lda, K;
  const unsigned short* A;
  const unsigned short* B;
  const int* alist = nullptr;
  unsigned short* H = nullptr;
  float* D = nullptr;
  int ldh = 0;

  if (MODE == 0) {
    if (ez < 8) {
      if (blockIdx.y >= 8) return;
      cnt = counts[ez]; A = Xb; alist = list + offs[ez]; lda = 1024; K = 1024;
      B = Wgu + (size_t)ez * 1024 * 1024; H = HeOut + (size_t)offs[ez] * 512; ldh = 512;
    } else {
      cnt = 2048; A = Xb; lda = 1024; K = 1024; B = Sgu; H = HsOut; ldh = 1024;
    }
  } else {
    if (ez < 8) {
      cnt = counts[ez]; A = He + (size_t)offs[ez] * 512; lda = 512; K = 512;
      B = Wd + (size_t)ez * 1024 * 512; D = De + (size_t)offs[ez] * 1024;
    } else {
      cnt = 2048; A = Hs; lda = 1024; K = 1024; B = Sd; D = Ds;
    }
  }

  const int m0 = blockIdx.x * 128;
  if (m0 >= cnt) return;
  const int n0 = blockIdx.y * 128;

  __shared__ unsigned short As[128 * 32];
  __shared__ unsigned short Bs[128 * 32];

  const int tid = threadIdx.x;
  const int srow = tid >> 2;
  const int scol = (tid & 3) * 8;
  const int wuni = (tid >> 6) * 512;

  int r0 = m0 + srow; if (r0 >= cnt) r0 = cnt - 1;
  int r1 = m0 + srow + 64; if (r1 >= cnt) r1 = cnt - 1;
  size_t abase0, abase1;
  if (MODE == 0 && ez < 8) {
    abase0 = (size_t)alist[r0] * lda; abase1 = (size_t)alist[r1] * lda;
  } else {
    abase0 = (size_t)r0 * lda; abase1 = (size_t)r1 * lda;
  }
  const size_t bbase0 = (size_t)(n0 + srow) * K;
  const size_t bbase1 = (size_t)(n0 + srow + 64) * K;

  const int wave = tid >> 6;
  const int lane = tid & 63;
  const int wm = (wave & 1) * 64;
  const int wn = (wave >> 1) * 64;
  const int fl = lane & 15;
  const int q = lane >> 4;

  f32x4 acc[4][4];
  f32x4 zero = {0.f, 0.f, 0.f, 0.f};
#pragma unroll
  for (int i = 0; i < 4; i++)
#pragma unroll
    for (int j = 0; j < 4; j++) acc[i][j] = zero;

  for (int k0 = 0; k0 < K; k0 += 32) {
    __syncthreads();
    gll16(A + abase0 + k0 + scol, &As[wuni]);
    gll16(A + abase1 + k0 + scol, &As[2048 + wuni]);
    gll16(B + bbase0 + k0 + scol, &Bs[wuni]);
    gll16(B + bbase1 + k0 + scol, &Bs[2048 + wuni]);
    __syncthreads();

    bf16x8 af[4], bfr[4];
#pragma unroll
    for (int i = 0; i < 4; i++) af[i] = *(const bf16x8*)(&As[(wm + i * 16 + fl) * 32 + q * 8]);
#pragma unroll
    for (int j = 0; j < 4; j++) bfr[j] = *(const bf16x8*)(&Bs[(wn + j * 16 + fl) * 32 + q * 8]);
#pragma unroll
    for (int i = 0; i < 4; i++)
#pragma unroll
      for (int j = 0; j < 4; j++)
        acc[i][j] = __builtin_amdgcn_mfma_f32_16x16x32_bf16(af[i], bfr[j], acc[i][j], 0, 0, 0);
  }

  if (MODE == 0) {
#pragma unroll
    for (int i = 0; i < 4; i++) {
#pragma unroll
      for (int j = 0; j < 4; j++) {
#pragma unroll
        for (int r = 0; r < 4; r++) {
          int grow = m0 + wm + i * 16 + q * 4 + r;
          float v = acc[i][j][r];
          float pv = __shfl_xor(v, 1);
          if ((lane & 1) == 0 && grow < cnt) {
            float s = v / (1.f + __expf(-v));
            int colh = (n0 + wn + j * 16 + fl) >> 1;
            H[(size_t)grow * ldh + colh] = f2bf(s * pv);
          }
        }
      }
    }
  } else {
#pragma unroll
    for (int i = 0; i < 4; i++) {
#pragma unroll
      for (int r = 0; r < 4; r++) {
        int grow = m0 + wm + i * 16 + q * 4 + r;
        if (grow >= cnt) continue;
#pragma unroll
        for (int j = 0; j < 4; j++) {
          int col = n0 + wn + j * 16 + fl;
          D[(size_t)grow * 1024 + col] = acc[i][j][r];
        }
      }
    }
  }
}

// ---------------- combine: out[t] = Ds[t] + p0*De[i0] + p1*De[i1] ----------------
__global__ __launch_bounds__(256) void combine_kernel(
    const float* __restrict__ Ds, const float* __restrict__ De,
    const int* __restrict__ ridx, const float* __restrict__ rp,
    float* __restrict__ out) {
  const int t = blockIdx.x;
  const int i0 = ridx[t * 2], i1 = ridx[t * 2 + 1];
  const float p0 = rp[t * 2], p1 = rp[t * 2 + 1];
  const float4* a  = (const float4*)(Ds + (size_t)t * 1024);
  const float4* b0 = (const float4*)(De + (size_t)i0 * 1024);
  const float4* b1 = (const float4*)(De + (size_t)i1 * 1024);
  float4* o = (float4*)(out + (size_t)t * 1024);
  int c = threadIdx.x;
  float4 va = a[c], v0 = b0[c], v1 = b1[c];
  float4 r;
  r.x = va.x + p0 * v0.x + p1 * v1.x;
  r.y = va.y + p0 * v0.y + p1 * v1.y;
  r.z = va.z + p0 * v0.z + p1 * v1.z;
  r.w = va.w + p0 * v0.w + p1 * v1.w;
  o[c] = r;
}

// ---------------- launch ----------------
extern "C" void kernel_launch(void* const* d_in, const int* in_sizes, int n_in,
                              void* d_out, int out_size, void* d_ws, size_t ws_size,
                              hipStream_t stream) {
  const float* x    = (const float*)d_in[0];
  const float* Wr   = (const float*)d_in[1];
  const float* Wg   = (const float*)d_in[2];
  const float* Wu   = (const float*)d_in[3];
  const float* Wd   = (const float*)d_in[4];
  const float* Sg   = (const float*)d_in[5];
  const float* Su   = (const float*)d_in[6];
  const float* Sd   = (const float*)d_in[7];
  const float* bias = (const float*)d_in[8];
  float* out = (float*)d_out;

  char* ws = (char*)d_ws;
  size_t o = 0;
  auto alloc = [&](size_t b) { char* p = ws + o; o += (b + 255) & ~(size_t)255; return p; };
  unsigned short* Xb   = (unsigned short*)alloc((size_t)2048 * 1024 * 2);
  unsigned short* WguT = (unsigned short*)alloc((size_t)8 * 1024 * 1024 * 2);
  unsigned short* WdT  = (unsigned short*)alloc((size_t)8 * 1024 * 512 * 2);
  unsigned short* SguT = (unsigned short*)alloc((size_t)2048 * 1024 * 2);
  unsigned short* SdT  = (unsigned short*)alloc((size_t)1024 * 1024 * 2);
  float* logits = (float*)alloc((size_t)2048 * 8 * 4);
  int*   list   = (int*)alloc((size_t)4096 * 4);
  int*   ridx   = (int*)alloc((size_t)2048 * 2 * 4);
  float* rp     = (float*)alloc((size_t)2048 * 2 * 4);
  int*   counts = (int*)alloc(64);
  int*   offs   = (int*)alloc(64);
  unsigned short* He = (unsigned short*)alloc((size_t)4096 * 512 * 2);
  unsigned short* Hs = (unsigned short*)alloc((size_t)2048 * 1024 * 2);
  float* De = (float*)alloc((size_t)4096 * 1024 * 4);
  float* Ds = (float*)alloc((size_t)2048 * 1024 * 4);

  cvt_bf16_kernel<<<2048, 256, 0, stream>>>(x, Xb, 2048 * 1024);
  transpose_cvt_kernel<<<dim3(16, 32, 8), 256, 0, stream>>>(Wg, WguT, 1024, 512,
                                                            524288L, 1048576L, 2048);
  transpose_cvt_kernel<<<dim3(16, 32, 8), 256, 0, stream>>>(Wu, WguT + 1024, 1024, 512,
                                                            524288L, 1048576L, 2048);
  transpose_cvt_kernel<<<dim3(32, 32, 1), 256, 0, stream>>>(Sg, SguT, 1024, 1024,
                                                            0L, 0L, 2048);
  transpose_cvt_kernel<<<dim3(32, 32, 1), 256, 0, stream>>>(Su, SguT + 1024, 1024, 1024,
                                                            0L, 0L, 2048);
  transpose_cvt_kernel<<<dim3(32, 16, 8), 256, 0, stream>>>(Wd, WdT, 512, 1024,
                                                            524288L, 524288L, 512);
  transpose_cvt_kernel<<<dim3(32, 32, 1), 256, 0, stream>>>(Sd, SdT, 1024, 1024,
                                                            0L, 0L, 1024);

  logits_kernel<<<512, 256, 0, stream>>>(x, Wr, logits);
  assign_kernel<<<1, 1024, 0, stream>>>(logits, bias, list, ridx, rp, counts, offs);

  gemm_tn_kernel<0><<<dim3(16, 16, 9), 256, 0, stream>>>(
      Xb, He, Hs, WguT, SguT, WdT, SdT, He, Hs, De, Ds, list, counts, offs);
  gemm_tn_kernel<1><<<dim3(16, 8, 9), 256, 0, stream>>>(
      Xb, He, Hs, WguT, SguT, WdT, SdT, He, Hs, De, Ds, list, counts, offs);

  combine_kernel<<<2048, 256, 0, stream>>>(Ds, De, ridx, rp, out);
}